// Round 6
// baseline (444.802 us; speedup 1.0000x reference)
//
#include <hip/hip_runtime.h>

// ---------------------------------------------------------------------------
// FasterMultiHeadAttention: B=2, S=2048, D=1024, H=16, HD=64  (fp32 in/out)
// R17 = R16 with attn occupancy attack (R16 counters: MFMA 27 + VALU 39,
// occ 34%, issue demand ~800cyc of 1900 -> latency-bound at 4 waves/SIMD,
// LDS-limited):
//  - V no longer staged in LDS: PV A-fragments (16B/lane) read direct from
//    global Vt, L2-resident (256KB/bh; XCD L2 4MB holds its bh-group's K+V).
//  - LDS halves to 32KB (K only, 2-buf) -> __launch_bounds__(512,6):
//    3 blocks/CU, 6 waves/SIMD (+50% latency hiding).
//  - q-tile 64, keys split 4-way across waves (wq 2 x kh 4), grid (32,32) =
//    1024 blocks; XCD-bijective swizzle pins bh-groups to one XCD's L2.
//  - cross-kh combine: 3-source LDS tree, per-nh rounds (24KB+1.5KB in Ks).
//  - per-wave state: qf 16 + sAcc 16 + o 32 ~= 84 VGPR (cap 85). Watch for
//    spill (WRITE_SIZE spike) -> revert occupancy bound if seen.
// prep / gemm_qkv / gemm_out unchanged from R16.
// ---------------------------------------------------------------------------

typedef __attribute__((ext_vector_type(8))) short bs8;      // 8 bf16 (4 VGPR)
typedef __attribute__((ext_vector_type(4))) short bs4;      // 4 bf16 (2 VGPR)
typedef __attribute__((ext_vector_type(4))) float f32x4;    // 16x16 MFMA acc
typedef __attribute__((ext_vector_type(16))) float f32x16;  // 32x32 MFMA acc

#define QSCALE 0.18033688011112042f  // (1/8) * log2(e)
#define MBOUND 24.0f                 // static softmax shift (scores |s| <~ 10)

// round-half-up fp32->bf16: error <= 0.5 ulp (same bound as RNE), 2 VALU ops
__device__ __forceinline__ unsigned short f2bf(float f) {
  union { float f; unsigned int u; } v; v.f = f;
  return (unsigned short)((v.u + 0x8000u) >> 16);
}

// pack two fp32 -> bf16 pair in ONE instruction (RNE). No builtin on gfx950.
__device__ __forceinline__ unsigned int cvtpk(float a, float b) {
#if defined(__HIP_DEVICE_COMPILE__)
  unsigned int r;
  asm("v_cvt_pk_bf16_f32 %0, %1, %2" : "=v"(r) : "v"(a), "v"(b));
  return r;
#else
  return 0u;  // host pass only type-checks
#endif
}

// v_permlane32_swap_b32: a.hi <-> b.lo  (a' = [a.lo|b.lo], b' = [a.hi|b.hi])
__device__ __forceinline__ void pls32(unsigned int &a, unsigned int &b) {
#if defined(__HIP_DEVICE_COMPILE__)
  asm("v_permlane32_swap_b32 %0, %1" : "+v"(a), "+v"(b));
#endif
}

// async global->LDS, 16B per lane. LDS dest = wave-uniform base + lane*16.
__device__ __forceinline__ void async16(const unsigned short* g, unsigned short* lds) {
  __builtin_amdgcn_global_load_lds(
      (const __attribute__((address_space(1))) unsigned int*)g,
      (__attribute__((address_space(3))) unsigned int*)lds, 16, 0, 0);
}

// Stage a 128-row x 64-col bf16 tile into LDS with chunk^(row&7) swizzle.
// 4-wave version: wave w covers rows [w*32, w*32+32).
__device__ __forceinline__ void stage_rows64(unsigned short* lds, const unsigned short* src,
                                             int ldk, int w, int l) {
#pragma unroll
  for (int i = 0; i < 4; ++i) {
    int row = (w * 4 + i) * 8 + (l >> 3);            // (row & 7) == (l>>3)
    int cg  = (l & 7) ^ (l >> 3);
    async16(src + (size_t)row * ldk + cg * 8, lds + (w * 4 + i) * 512);
  }
}

// 8-wave version: wave w covers rows [w*16, w*16+16).
__device__ __forceinline__ void stage_rows64_8w(unsigned short* lds, const unsigned short* src,
                                                int ldk, int w, int l) {
#pragma unroll
  for (int i = 0; i < 2; ++i) {
    int row = (w * 2 + i) * 8 + (l >> 3);
    int cg  = (l & 7) ^ (l >> 3);
    async16(src + (size_t)row * ldk + cg * 8, lds + (w * 2 + i) * 512);
  }
}

// ---------------------------------------------------------------------------
// Fused prep: blocks [0,2048): cast x -> bf16; [2048,2816): transpose w_qkv;
// [2816,3072): transpose w_out. One launch, jobs overlap across CUs.
// ---------------------------------------------------------------------------
__device__ __forceinline__ void transpose_cast_body(const float* __restrict__ src,
                                                    unsigned short* __restrict__ dst,
                                                    int R, int C, int bx, int by, int t) {
  __shared__ unsigned short tile[64][73];
  int c0 = bx * 64, r0 = by * 64;
  int rl = t >> 2, cb = (t & 3) * 16;
  const float* p = src + (size_t)(r0 + rl) * C + c0 + cb;
#pragma unroll
  for (int j = 0; j < 16; j += 4) {
    float4 f = *(const float4*)(p + j);
    tile[rl][cb + j + 0] = f2bf(f.x);
    tile[rl][cb + j + 1] = f2bf(f.y);
    tile[rl][cb + j + 2] = f2bf(f.z);
    tile[rl][cb + j + 3] = f2bf(f.w);
  }
  __syncthreads();
  int cl = t >> 2, rb = (t & 3) * 16;
  unsigned short* q = dst + (size_t)(c0 + cl) * R + r0 + rb;
#pragma unroll
  for (int j = 0; j < 16; ++j) q[j] = tile[rb + j][cl];
}

__global__ __launch_bounds__(256) void prep_kernel(const float* __restrict__ x,
                                                   unsigned short* __restrict__ xb,
                                                   const float* __restrict__ w_qkv,
                                                   unsigned short* __restrict__ wt1,
                                                   const float* __restrict__ w_out,
                                                   unsigned short* __restrict__ wt2) {
  int blk = blockIdx.x, t = threadIdx.x;
  if (blk < 2048) {
    int i = (blk * 256 + t) * 8;
    float4 a = *(const float4*)(x + i);
    float4 b = *(const float4*)(x + i + 4);
    union { bs8 v; unsigned short u[8]; } o;
    o.u[0] = f2bf(a.x); o.u[1] = f2bf(a.y); o.u[2] = f2bf(a.z); o.u[3] = f2bf(a.w);
    o.u[4] = f2bf(b.x); o.u[5] = f2bf(b.y); o.u[6] = f2bf(b.z); o.u[7] = f2bf(b.w);
    *(bs8*)(xb + i) = o.v;
  } else if (blk < 2816) {
    int i = blk - 2048;                       // 768 blocks = 48 x 16
    transpose_cast_body(w_qkv, wt1, 1024, 3072, i % 48, i / 48, t);
  } else {
    int i = blk - 2816;                       // 256 blocks = 16 x 16
    transpose_cast_body(w_out, wt2, 1024, 1024, i % 16, i / 16, t);
  }
}

// ---------------------------------------------------------------------------
// QKV GEMM (m97 structure): A [4096][1024] bf16, Bt [3072][1024] bf16.
// 128x128 block tile, 256 threads / 4 waves, wave tile 64x64, 4x4 acc, BK=64.
// Q/K blocks (bn<16): transposed C (r spans hd) -> b64 stores to [bh][s][hd].
// V blocks (bn>=16): standard C (r spans s)  -> b64 stores to Vt [bh][hd][s]
// (LINEAR layout).
// ---------------------------------------------------------------------------
__global__ __launch_bounds__(256) void gemm_qkv_kernel(const unsigned short* __restrict__ A,
                                                       const unsigned short* __restrict__ Bt,
                                                       const float* __restrict__ bias,
                                                       unsigned short* __restrict__ qo,
                                                       unsigned short* __restrict__ ko,
                                                       unsigned short* __restrict__ vto) {
  __shared__ unsigned short As[128 * 64];
  __shared__ unsigned short Bs[128 * 64];
  int t = threadIdx.x, w = t >> 6, l = t & 63;
  int m16 = l & 15, q = l >> 4;
  int wm = w >> 1, wn = w & 1;          // 64-token / 64-feature wave tile
  int bm = blockIdx.y, bn = blockIdx.x;
  bool vsec = (bn >= 16);               // block-uniform section select
  const unsigned short* Abase = A + (size_t)bm * 128 * 1024;
  const unsigned short* Bbase = Bt + (size_t)bn * 128 * 1024;
  f32x4 zero4 = {0.f, 0.f, 0.f, 0.f};
  f32x4 acc[4][4];
#pragma unroll
  for (int i = 0; i < 4; ++i)
#pragma unroll
    for (int j = 0; j < 4; ++j) acc[i][j] = zero4;
  for (int kt = 0; kt < 16; ++kt) {
    stage_rows64(As, Abase + kt * 64, 1024, w, l);
    stage_rows64(Bs, Bbase + kt * 64, 1024, w, l);
    __syncthreads();
#pragma unroll
    for (int ks = 0; ks < 2; ++ks) {
      bs8 af[4], bf[4];
#pragma unroll
      for (int mt = 0; mt < 4; ++mt) {
        int row = wm * 64 + mt * 16 + m16;
        int c = ks * 4 + q;
        af[mt] = *(const bs8*)&As[row * 64 + ((c ^ (row & 7)) * 8)];
      }
#pragma unroll
      for (int nt = 0; nt < 4; ++nt) {
        int row = wn * 64 + nt * 16 + m16;
        int c = ks * 4 + q;
        bf[nt] = *(const bs8*)&Bs[row * 64 + ((c ^ (row & 7)) * 8)];
      }
      if (vsec) {
        // standard: C[row=token][col=feature]
#pragma unroll
        for (int mt = 0; mt < 4; ++mt)
#pragma unroll
          for (int nt = 0; nt < 4; ++nt)
            acc[mt][nt] = __builtin_amdgcn_mfma_f32_16x16x32_bf16(af[mt], bf[nt],
                                                                  acc[mt][nt], 0, 0, 0);
      } else {
        // transposed: C[row=feature][col=token]
#pragma unroll
        for (int mt = 0; mt < 4; ++mt)
#pragma unroll
          for (int nt = 0; nt < 4; ++nt)
            acc[mt][nt] = __builtin_amdgcn_mfma_f32_16x16x32_bf16(bf[nt], af[mt],
                                                                  acc[mt][nt], 0, 0, 0);
      }
    }
    __syncthreads();
  }
  if (!vsec) {
    // ---- Q/K epilogue (transposed C): r spans 4 consecutive hd -> b64 store
#pragma unroll
    for (int nt = 0; nt < 4; ++nt) {
      int ng0 = bn * 128 + wn * 64 + nt * 16 + q * 4;
      float4 bb = *(const float4*)&bias[ng0];
      int sect = ng0 >> 10;             // 0=Q 1=K
      unsigned short* dst = sect ? ko : qo;
      float sc = sect ? 1.0f : QSCALE;
      int f0 = ng0 & 1023, h = f0 >> 6, hd0 = f0 & 63;
#pragma unroll
      for (int mt = 0; mt < 4; ++mt) {
        int mg = bm * 128 + wm * 64 + mt * 16 + m16;
        int b = mg >> 11, s = mg & 2047;
        union { bs4 v; unsigned short u[4]; } pv;
        pv.u[0] = f2bf((acc[mt][nt][0] + bb.x) * sc);
        pv.u[1] = f2bf((acc[mt][nt][1] + bb.y) * sc);
        pv.u[2] = f2bf((acc[mt][nt][2] + bb.z) * sc);
        pv.u[3] = f2bf((acc[mt][nt][3] + bb.w) * sc);
        *(bs4*)&dst[((size_t)(b * 16 + h) * 2048 + s) * 64 + hd0] = pv.v;
      }
    }
  } else {
    // ---- V epilogue (standard C): r spans 4 consecutive s -> b64 to Vt
#pragma unroll
    for (int nt = 0; nt < 4; ++nt) {
      int ng = bn * 128 + wn * 64 + nt * 16 + m16;
      float bb = bias[ng];
      int f = ng & 1023, h = f >> 6, hd = f & 63;
#pragma unroll
      for (int mt = 0; mt < 4; ++mt) {
        int mg0 = bm * 128 + wm * 64 + mt * 16 + q * 4;
        int b = mg0 >> 11, s0 = mg0 & 2047;
        union { bs4 v; unsigned short u[4]; } pv;
#pragma unroll
        for (int r = 0; r < 4; ++r) pv.u[r] = f2bf(acc[mt][nt][r] + bb);
        *(bs4*)&vto[((size_t)(b * 16 + h) * 64 + hd) * 2048 + s0] = pv.v;
      }
    }
  }
}

// ---------------------------------------------------------------------------
// Out GEMM: 64x128 block tile, 256 threads / 4 waves, wave tile 32x64 (2x2).
// Grid (8, 64) = 512 blocks -> 2 independent blocks/CU. Transposed C:
// r spans 4 consecutive output features -> float4 stores.
// ---------------------------------------------------------------------------
__global__ __launch_bounds__(256) void gemm_out_kernel(const unsigned short* __restrict__ A,
                                                       const unsigned short* __restrict__ Bt,
                                                       const float* __restrict__ bias,
                                                       float* __restrict__ out) {
  __shared__ unsigned short As[64 * 64];    // 8 KB
  __shared__ unsigned short Bs[128 * 64];   // 16 KB
  int t = threadIdx.x, w = t >> 6, l = t & 63;
  int m16 = l & 15, q = l >> 4;
  int wm = w >> 1, wn = w & 1;          // wm 0..1 (32-token), wn 0..1 (64-feature)
  int bm = blockIdx.y, bn = blockIdx.x;
  const unsigned short* Abase = A + (size_t)bm * 64 * 1024;
  const unsigned short* Bbase = Bt + (size_t)bn * 128 * 1024;
  f32x4 zero4 = {0.f, 0.f, 0.f, 0.f};
  f32x4 acc[2][4];
#pragma unroll
  for (int i = 0; i < 2; ++i)
#pragma unroll
    for (int j = 0; j < 4; ++j) acc[i][j] = zero4;
  for (int kt = 0; kt < 16; ++kt) {
    stage_rows64_8w(As, Abase + kt * 64, 1024, w, l);   // w 0..3 covers rows 0..63
    stage_rows64(Bs, Bbase + kt * 64, 1024, w, l);      // 4-wave, 128 rows
    __syncthreads();
#pragma unroll
    for (int ks = 0; ks < 2; ++ks) {
      bs8 af[2], bf[4];
#pragma unroll
      for (int mt = 0; mt < 2; ++mt) {
        int row = wm * 32 + mt * 16 + m16;
        int c = ks * 4 + q;
        af[mt] = *(const bs8*)&As[row * 64 + ((c ^ (row & 7)) * 8)];
      }
#pragma unroll
      for (int nt = 0; nt < 4; ++nt) {
        int row = wn * 64 + nt * 16 + m16;
        int c = ks * 4 + q;
        bf[nt] = *(const bs8*)&Bs[row * 64 + ((c ^ (row & 7)) * 8)];
      }
#pragma unroll
      for (int mt = 0; mt < 2; ++mt)
#pragma unroll
        for (int nt = 0; nt < 4; ++nt)
          acc[mt][nt] = __builtin_amdgcn_mfma_f32_16x16x32_bf16(bf[nt], af[mt],
                                                                acc[mt][nt], 0, 0, 0);
    }
    __syncthreads();
  }
#pragma unroll
  for (int nt = 0; nt < 4; ++nt) {
    int ng0 = bn * 128 + wn * 64 + nt * 16 + q * 4;
    float4 bb = *(const float4*)&bias[ng0];
#pragma unroll
    for (int mt = 0; mt < 2; ++mt) {
      int mg = bm * 64 + wm * 32 + mt * 16 + m16;
      float4 ov;
      ov.x = acc[mt][nt][0] + bb.x;
      ov.y = acc[mt][nt][1] + bb.y;
      ov.z = acc[mt][nt][2] + bb.z;
      ov.w = acc[mt][nt][3] + bb.w;
      *(float4*)&out[(size_t)mg * 1024 + ng0] = ov;
    }
  }
}

// ---------------------------------------------------------------------------
// Flash attention, 32x32x16 MFMAs, S^T form, static-max softmax. R17:
// grid (32 qt, 32 bh) XCD-swizzled -> 1024 blocks, 512 thr / 8 waves.
// Wave w: wq = w&1 (queries wq*32..+31 of a 64-q tile), kh = w>>1 (keys
// kh*32..+31 of each 128-key tile). 16 iters, one barrier/iter.
// LDS: K only, double-buffered, 32KB. V read direct from global (L2).
// QK: sAcc = mfma(K,Q) over ks 0..3. exp2+cvt_pk+permlane -> PV B-frag.
// PV: o[nh] = mfma(Vt-global-frag, P, o[nh]). 4-way kh combine via LDS tree.
// ---------------------------------------------------------------------------
__global__ __launch_bounds__(512, 6) void attn_kernel(const unsigned short* __restrict__ Q,
                                                      const unsigned short* __restrict__ K,
                                                      const unsigned short* __restrict__ Vt,
                                                      unsigned short* __restrict__ Aout) {
  __shared__ unsigned short Ks[2][128 * 64];    // 32 KB total
  int t = threadIdx.x, w = t >> 6, l = t & 63;
  int c32 = l & 31, lh = l >> 5;                // query column / lane half
  int wq = w & 1, kh = w >> 1;                  // query group / key quarter
  // XCD-bijective swizzle: 1024 blocks = 8 XCDs x 128; each XCD owns 4 bh.
  int lid = blockIdx.y * 32 + blockIdx.x;
  int swz = (lid & 7) * 128 + (lid >> 3);
  int qt = swz & 31, bh = swz >> 5;
  const unsigned short* qbase = Q + (size_t)bh * 2048 * 64 + (size_t)qt * 64 * 64;
  const unsigned short* kbase = K + (size_t)bh * 2048 * 64;
  const unsigned short* vtbase = Vt + (size_t)bh * 64 * 2048;

  // Q fragments (B-operand): qf[ks] = Q[wq*32+c32][ks*16 + lh*8 ..+7]
  bs8 qf[4];
#pragma unroll
  for (int ks = 0; ks < 4; ++ks)
    qf[ks] = *(const bs8*)(qbase + (size_t)(wq * 32 + c32) * 64 + ks * 16 + lh * 8);

  stage_rows64_8w(&Ks[0][0], kbase, 64, w, l);
  __syncthreads();

  f32x16 sAcc;
  f32x16 o[2];
  float lsum = 0.f;
#pragma unroll
  for (int r = 0; r < 16; ++r) { o[0][r] = 0.f; o[1][r] = 0.f; }

  int krow = kh * 32 + c32;                     // this lane's K row (0..127)
  for (int kt = 0; kt < 16; ++kt) {
    int buf = kt & 1;
    if (kt < 15)
      stage_rows64_8w(&Ks[buf ^ 1][0], kbase + (size_t)(kt + 1) * 128 * 64, 64, w, l);
    const unsigned short* Kb = &Ks[buf][0];

    // ---- S^T tile over this wave's 32 keys
#pragma unroll
    for (int r = 0; r < 16; ++r) sAcc[r] = -MBOUND;
#pragma unroll
    for (int ks = 0; ks < 4; ++ks) {
      int cgr = ks * 2 + lh;
      bs8 kf = *(const bs8*)&Kb[krow * 64 + ((cgr ^ (krow & 7)) * 8)];
      __builtin_amdgcn_s_setprio(1);
      sAcc = __builtin_amdgcn_mfma_f32_32x32x16_bf16(kf, qf[ks], sAcc, 0, 0, 0);
      __builtin_amdgcn_s_setprio(0);
    }

    // ---- exp2 + cvt_pk pack
    float rs = 0.f;
    unsigned int wp[8];
#pragma unroll
    for (int ri = 0; ri < 8; ++ri) {
      float p0 = __builtin_amdgcn_exp2f(sAcc[2 * ri]);
      float p1 = __builtin_amdgcn_exp2f(sAcc[2 * ri + 1]);
      rs += p0 + p1;
      wp[ri] = cvtpk(p0, p1);
    }
    lsum += rs;

    // ---- permlane redistribute + PV (V from global, L2-resident)
#pragma unroll
    for (int kp = 0; kp < 2; ++kp) {
      unsigned int W0 = wp[kp * 4 + 0], W2 = wp[kp * 4 + 2];
      unsigned int W1 = wp[kp * 4 + 1], W3 = wp[kp * 4 + 3];
      pls32(W0, W2);                            // -> B words 0 and 2
      pls32(W1, W3);                            // -> B words 1 and 3
      union { bs8 v; unsigned int u[4]; } pf;
      pf.u[0] = W0; pf.u[1] = W1; pf.u[2] = W2; pf.u[3] = W3;
      __builtin_amdgcn_s_setprio(1);
#pragma unroll
      for (int nh = 0; nh < 2; ++nh) {
        const unsigned short* vp = vtbase + (size_t)(nh * 32 + c32) * 2048 +
                                   kt * 128 + kh * 32 + kp * 16 + lh * 8;
        bs8 vf = *(const bs8*)vp;
        o[nh] = __builtin_amdgcn_mfma_f32_32x32x16_bf16(vf, pf.v, o[nh], 0, 0, 0);
      }
      __builtin_amdgcn_s_setprio(0);
    }
    __syncthreads();
  }

  // ---- 4-way kh combine via LDS tree (Ks reused; 8192 floats available).
  // Per-nh round: kh 1..3 publish 4 quads at region (kh-1)*2048 (24KB);
  // lsum published once at floats[6144..6528). kh=0 accumulates.
  float* fs = (float*)&Ks[0][0];
  int slot = wq * 64 + l;                       // 0..127
#pragma unroll
  for (int nh = 0; nh < 2; ++nh) {
    if (kh != 0) {
      int base = (kh - 1) * 2048 + slot * 16;
#pragma unroll
      for (int c = 0; c < 4; ++c) {
        f32x4 t4 = { o[nh][c * 4 + 0], o[nh][c * 4 + 1],
                     o[nh][c * 4 + 2], o[nh][c * 4 + 3] };
        *(f32x4*)&fs[base + c * 4] = t4;
      }
      if (nh == 0) fs[6144 + (kh - 1) * 128 + slot] = lsum;
    }
    __syncthreads();
    if (kh == 0) {
#pragma unroll
      for (int kk = 1; kk < 4; ++kk) {
        int base = (kk - 1) * 2048 + slot * 16;
#pragma unroll
        for (int c = 0; c < 4; ++c) {
          f32x4 part = *(const f32x4*)&fs[base + c * 4];
#pragma unroll
          for (int r = 0; r < 4; ++r) o[nh][c * 4 + r] += part[r];
        }
        if (nh == 0) lsum += fs[6144 + (kk - 1) * 128 + slot];
      }
    }
    __syncthreads();
  }

  // ---- normalize + restage bf16 O through LDS (granule-swizzled, 8KB)
  unsigned short* ot = &Ks[0][0];
  int b = bh >> 4, hh = bh & 15;
  if (kh == 0) {
    float l0 = lsum;
    l0 += __shfl_xor(l0, 32);                   // lane halves: disjoint keys
    float inv = 1.0f / l0;
    int token = wq * 32 + c32;
#pragma unroll
    for (int nh = 0; nh < 2; ++nh)
#pragma unroll
      for (int rg = 0; rg < 4; ++rg) {
        union { bs4 v; unsigned int u[2]; } pv;
        pv.u[0] = cvtpk(o[nh][rg * 4 + 0] * inv, o[nh][rg * 4 + 1] * inv);
        pv.u[1] = cvtpk(o[nh][rg * 4 + 2] * inv, o[nh][rg * 4 + 3] * inv);
        int g = nh * 4 + rg;                    // 16B hd-granule index
        *(bs4*)&ot[token * 64 + ((g ^ (token & 7)) * 8) + lh * 4] = pv.v;
      }
  }
  __syncthreads();
  // ---- coalesced store: 512 threads x 16B = full 128B per token row
  {
    int token = t >> 3, g = t & 7;              // 64 tokens x 8 granules
    bs8 val = *(const bs8*)&ot[token * 64 + ((g ^ (token & 7)) * 8)];
    *(bs8*)&Aout[((size_t)(b * 2048 + qt * 64 + token)) * 1024 + hh * 64 + g * 8] = val;
  }
}

// ---------------------------------------------------------------------------
extern "C" void kernel_launch(void* const* d_in, const int* in_sizes, int n_in,
                              void* d_out, int out_size, void* d_ws, size_t ws_size,
                              hipStream_t stream) {
  const float* x     = (const float*)d_in[0];   // [2,2048,1024]
  const float* w_qkv = (const float*)d_in[1];   // [1024,3072]
  const float* b_qkv = (const float*)d_in[2];   // [3072]
  const float* w_out = (const float*)d_in[3];   // [1024,1024]
  const float* b_out = (const float*)d_in[4];   // [1024]
  float* out = (float*)d_out;                   // [2,2048,1024] fp32

  char* ws = (char*)d_ws;                       // needs 48 MB
  unsigned short* xb    = (unsigned short*)(ws);                     // 8 MB
  unsigned short* wt1   = (unsigned short*)(ws + (8u << 20));        // 6 MB
  unsigned short* wt2   = (unsigned short*)(ws + (14u << 20));       // 2 MB
  unsigned short* qb    = (unsigned short*)(ws + (16u << 20));       // 8 MB
  unsigned short* kb    = (unsigned short*)(ws + (24u << 20));       // 8 MB
  unsigned short* vtb   = (unsigned short*)(ws + (32u << 20));       // 8 MB
  unsigned short* attnb = (unsigned short*)(ws + (40u << 20));       // 8 MB

  prep_kernel<<<3072, 256, 0, stream>>>(x, xb, w_qkv, wt1, w_out, wt2);
  gemm_qkv_kernel<<<dim3(24, 32), 256, 0, stream>>>(xb, wt1, b_qkv, qb, kb, vtb);
  attn_kernel<<<dim3(32, 32), 512, 0, stream>>>(qb, kb, vtb, attnb);
  gemm_out_kernel<<<dim3(8, 64), 256, 0, stream>>>(attnb, wt2, b_out, out);
}

// Round 9
// 186.154 us; speedup vs baseline: 2.3894x; 2.3894x over previous
//
#include <hip/hip_runtime.h>

// ---------------------------------------------------------------------------
// FasterMultiHeadAttention: B=2, S=2048, D=1024, H=16, HD=64  (fp32 in/out)
// R20 = EXACT R16 (last harness-verified: passed, E2E 189.3us, attn 50.9us)
// + XCD-bijective block swizzles ONLY (provably-bijective index remaps, the
// same form present in the PASSING R17; zero dataflow/barrier/layout change):
//  - attn: 512 blocks = 8 XCDs x 64 -> 4 bh (2MB K+V) pinned per XCD L2.
//  - gemm_qkv: 768 = 8 x 96 -> 4 bm A-panels (1MB) resident per XCD.
//  - gemm_out: 512 = 8 x 64 -> 8 bm A-panels resident per XCD.
// R18/R19 post-mortem: two consecutive correctness failures on the
// V-direct-global + combine-restructure composition, undiagnosable by
// inspection -> abandoned that branch, returned to verified base.
// ---------------------------------------------------------------------------

typedef __attribute__((ext_vector_type(8))) short bs8;      // 8 bf16 (4 VGPR)
typedef __attribute__((ext_vector_type(4))) short bs4;      // 4 bf16 (2 VGPR)
typedef __attribute__((ext_vector_type(4))) float f32x4;    // 16x16 MFMA acc
typedef __attribute__((ext_vector_type(16))) float f32x16;  // 32x32 MFMA acc

#define QSCALE 0.18033688011112042f  // (1/8) * log2(e)
#define MBOUND 24.0f                 // static softmax shift (scores |s| <~ 10)

// round-half-up fp32->bf16: error <= 0.5 ulp (same bound as RNE), 2 VALU ops
__device__ __forceinline__ unsigned short f2bf(float f) {
  union { float f; unsigned int u; } v; v.f = f;
  return (unsigned short)((v.u + 0x8000u) >> 16);
}

// pack two fp32 -> bf16 pair in ONE instruction (RNE). No builtin on gfx950.
__device__ __forceinline__ unsigned int cvtpk(float a, float b) {
#if defined(__HIP_DEVICE_COMPILE__)
  unsigned int r;
  asm("v_cvt_pk_bf16_f32 %0, %1, %2" : "=v"(r) : "v"(a), "v"(b));
  return r;
#else
  return 0u;  // host pass only type-checks
#endif
}

// v_permlane32_swap_b32: a.hi <-> b.lo  (a' = [a.lo|b.lo], b' = [a.hi|b.hi])
__device__ __forceinline__ void pls32(unsigned int &a, unsigned int &b) {
#if defined(__HIP_DEVICE_COMPILE__)
  asm("v_permlane32_swap_b32 %0, %1" : "+v"(a), "+v"(b));
#endif
}

// async global->LDS, 16B per lane. LDS dest = wave-uniform base + lane*16.
__device__ __forceinline__ void async16(const unsigned short* g, unsigned short* lds) {
  __builtin_amdgcn_global_load_lds(
      (const __attribute__((address_space(1))) unsigned int*)g,
      (__attribute__((address_space(3))) unsigned int*)lds, 16, 0, 0);
}

// Stage a 128-row x 64-col bf16 tile into LDS with chunk^(row&7) swizzle.
// 4-wave version: wave w covers rows [w*32, w*32+32).
__device__ __forceinline__ void stage_rows64(unsigned short* lds, const unsigned short* src,
                                             int ldk, int w, int l) {
#pragma unroll
  for (int i = 0; i < 4; ++i) {
    int row = (w * 4 + i) * 8 + (l >> 3);            // (row & 7) == (l>>3)
    int cg  = (l & 7) ^ (l >> 3);
    async16(src + (size_t)row * ldk + cg * 8, lds + (w * 4 + i) * 512);
  }
}

// 8-wave version: wave w covers rows [w*16, w*16+16).
__device__ __forceinline__ void stage_rows64_8w(unsigned short* lds, const unsigned short* src,
                                                int ldk, int w, int l) {
#pragma unroll
  for (int i = 0; i < 2; ++i) {
    int row = (w * 2 + i) * 8 + (l >> 3);
    int cg  = (l & 7) ^ (l >> 3);
    async16(src + (size_t)row * ldk + cg * 8, lds + (w * 2 + i) * 512);
  }
}

// 64-row x 128-col Vt slice (row stride 2048), 8 waves, chunk^(row&15).
__device__ __forceinline__ void stage_vt_8w(unsigned short* lds, const unsigned short* vtb,
                                            int keyofs, int w, int l) {
#pragma unroll
  for (int i = 0; i < 2; ++i) {
    int row = (w * 2 + i) * 4 + (l >> 4);
    int cg = (l & 15) ^ (row & 15);
    async16(vtb + (size_t)row * 2048 + keyofs + cg * 8, lds + (w * 2 + i) * 512);
  }
}

// ---------------------------------------------------------------------------
// Fused prep: blocks [0,2048): cast x -> bf16; [2048,2816): transpose w_qkv;
// [2816,3072): transpose w_out. One launch, jobs overlap across CUs.
// ---------------------------------------------------------------------------
__device__ __forceinline__ void transpose_cast_body(const float* __restrict__ src,
                                                    unsigned short* __restrict__ dst,
                                                    int R, int C, int bx, int by, int t) {
  __shared__ unsigned short tile[64][73];
  int c0 = bx * 64, r0 = by * 64;
  int rl = t >> 2, cb = (t & 3) * 16;
  const float* p = src + (size_t)(r0 + rl) * C + c0 + cb;
#pragma unroll
  for (int j = 0; j < 16; j += 4) {
    float4 f = *(const float4*)(p + j);
    tile[rl][cb + j + 0] = f2bf(f.x);
    tile[rl][cb + j + 1] = f2bf(f.y);
    tile[rl][cb + j + 2] = f2bf(f.z);
    tile[rl][cb + j + 3] = f2bf(f.w);
  }
  __syncthreads();
  int cl = t >> 2, rb = (t & 3) * 16;
  unsigned short* q = dst + (size_t)(c0 + cl) * R + r0 + rb;
#pragma unroll
  for (int j = 0; j < 16; ++j) q[j] = tile[rb + j][cl];
}

__global__ __launch_bounds__(256) void prep_kernel(const float* __restrict__ x,
                                                   unsigned short* __restrict__ xb,
                                                   const float* __restrict__ w_qkv,
                                                   unsigned short* __restrict__ wt1,
                                                   const float* __restrict__ w_out,
                                                   unsigned short* __restrict__ wt2) {
  int blk = blockIdx.x, t = threadIdx.x;
  if (blk < 2048) {
    int i = (blk * 256 + t) * 8;
    float4 a = *(const float4*)(x + i);
    float4 b = *(const float4*)(x + i + 4);
    union { bs8 v; unsigned short u[8]; } o;
    o.u[0] = f2bf(a.x); o.u[1] = f2bf(a.y); o.u[2] = f2bf(a.z); o.u[3] = f2bf(a.w);
    o.u[4] = f2bf(b.x); o.u[5] = f2bf(b.y); o.u[6] = f2bf(b.z); o.u[7] = f2bf(b.w);
    *(bs8*)(xb + i) = o.v;
  } else if (blk < 2816) {
    int i = blk - 2048;                       // 768 blocks = 48 x 16
    transpose_cast_body(w_qkv, wt1, 1024, 3072, i % 48, i / 48, t);
  } else {
    int i = blk - 2816;                       // 256 blocks = 16 x 16
    transpose_cast_body(w_out, wt2, 1024, 1024, i % 16, i / 16, t);
  }
}

// ---------------------------------------------------------------------------
// QKV GEMM (m97 structure): A [4096][1024] bf16, Bt [3072][1024] bf16.
// 128x128 block tile, 256 threads / 4 waves, wave tile 64x64, 4x4 acc, BK=64.
// Q/K blocks (bn<16): transposed C (r spans hd) -> b64 stores to [bh][s][hd].
// V blocks (bn>=16): standard C (r spans s)  -> b64 stores to Vt [bh][hd][s]
// (LINEAR layout). R20: XCD-bijective swizzle (768 = 8 x 96).
// ---------------------------------------------------------------------------
__global__ __launch_bounds__(256) void gemm_qkv_kernel(const unsigned short* __restrict__ A,
                                                       const unsigned short* __restrict__ Bt,
                                                       const float* __restrict__ bias,
                                                       unsigned short* __restrict__ qo,
                                                       unsigned short* __restrict__ ko,
                                                       unsigned short* __restrict__ vto) {
  __shared__ unsigned short As[128 * 64];
  __shared__ unsigned short Bs[128 * 64];
  int t = threadIdx.x, w = t >> 6, l = t & 63;
  int m16 = l & 15, q = l >> 4;
  int wm = w >> 1, wn = w & 1;          // 64-token / 64-feature wave tile
  // XCD-bijective swizzle: 768 blocks = 8 XCDs x 96 -> 4 bm rows per XCD.
  int lid = blockIdx.y * 24 + blockIdx.x;
  int swz = (lid & 7) * 96 + (lid >> 3);
  int bn = swz % 24, bm = swz / 24;
  bool vsec = (bn >= 16);               // block-uniform section select
  const unsigned short* Abase = A + (size_t)bm * 128 * 1024;
  const unsigned short* Bbase = Bt + (size_t)bn * 128 * 1024;
  f32x4 zero4 = {0.f, 0.f, 0.f, 0.f};
  f32x4 acc[4][4];
#pragma unroll
  for (int i = 0; i < 4; ++i)
#pragma unroll
    for (int j = 0; j < 4; ++j) acc[i][j] = zero4;
  for (int kt = 0; kt < 16; ++kt) {
    stage_rows64(As, Abase + kt * 64, 1024, w, l);
    stage_rows64(Bs, Bbase + kt * 64, 1024, w, l);
    __syncthreads();
#pragma unroll
    for (int ks = 0; ks < 2; ++ks) {
      bs8 af[4], bf[4];
#pragma unroll
      for (int mt = 0; mt < 4; ++mt) {
        int row = wm * 64 + mt * 16 + m16;
        int c = ks * 4 + q;
        af[mt] = *(const bs8*)&As[row * 64 + ((c ^ (row & 7)) * 8)];
      }
#pragma unroll
      for (int nt = 0; nt < 4; ++nt) {
        int row = wn * 64 + nt * 16 + m16;
        int c = ks * 4 + q;
        bf[nt] = *(const bs8*)&Bs[row * 64 + ((c ^ (row & 7)) * 8)];
      }
      if (vsec) {
        // standard: C[row=token][col=feature]
#pragma unroll
        for (int mt = 0; mt < 4; ++mt)
#pragma unroll
          for (int nt = 0; nt < 4; ++nt)
            acc[mt][nt] = __builtin_amdgcn_mfma_f32_16x16x32_bf16(af[mt], bf[nt],
                                                                  acc[mt][nt], 0, 0, 0);
      } else {
        // transposed: C[row=feature][col=token]
#pragma unroll
        for (int mt = 0; mt < 4; ++mt)
#pragma unroll
          for (int nt = 0; nt < 4; ++nt)
            acc[mt][nt] = __builtin_amdgcn_mfma_f32_16x16x32_bf16(bf[nt], af[mt],
                                                                  acc[mt][nt], 0, 0, 0);
      }
    }
    __syncthreads();
  }
  if (!vsec) {
    // ---- Q/K epilogue (transposed C): r spans 4 consecutive hd -> b64 store
#pragma unroll
    for (int nt = 0; nt < 4; ++nt) {
      int ng0 = bn * 128 + wn * 64 + nt * 16 + q * 4;
      float4 bb = *(const float4*)&bias[ng0];
      int sect = ng0 >> 10;             // 0=Q 1=K
      unsigned short* dst = sect ? ko : qo;
      float sc = sect ? 1.0f : QSCALE;
      int f0 = ng0 & 1023, h = f0 >> 6, hd0 = f0 & 63;
#pragma unroll
      for (int mt = 0; mt < 4; ++mt) {
        int mg = bm * 128 + wm * 64 + mt * 16 + m16;
        int b = mg >> 11, s = mg & 2047;
        union { bs4 v; unsigned short u[4]; } pv;
        pv.u[0] = f2bf((acc[mt][nt][0] + bb.x) * sc);
        pv.u[1] = f2bf((acc[mt][nt][1] + bb.y) * sc);
        pv.u[2] = f2bf((acc[mt][nt][2] + bb.z) * sc);
        pv.u[3] = f2bf((acc[mt][nt][3] + bb.w) * sc);
        *(bs4*)&dst[((size_t)(b * 16 + h) * 2048 + s) * 64 + hd0] = pv.v;
      }
    }
  } else {
    // ---- V epilogue (standard C): r spans 4 consecutive s -> b64 to Vt
#pragma unroll
    for (int nt = 0; nt < 4; ++nt) {
      int ng = bn * 128 + wn * 64 + nt * 16 + m16;
      float bb = bias[ng];
      int f = ng & 1023, h = f >> 6, hd = f & 63;
#pragma unroll
      for (int mt = 0; mt < 4; ++mt) {
        int mg0 = bm * 128 + wm * 64 + mt * 16 + q * 4;
        int b = mg0 >> 11, s0 = mg0 & 2047;
        union { bs4 v; unsigned short u[4]; } pv;
#pragma unroll
        for (int r = 0; r < 4; ++r) pv.u[r] = f2bf(acc[mt][nt][r] + bb);
        *(bs4*)&vto[((size_t)(b * 16 + h) * 64 + hd) * 2048 + s0] = pv.v;
      }
    }
  }
}

// ---------------------------------------------------------------------------
// Out GEMM: 64x128 block tile, 256 threads / 4 waves, wave tile 32x64 (2x2).
// Grid 512 blocks -> 2 independent blocks/CU. Transposed C: r spans 4
// consecutive output features -> float4 stores. R20: XCD swizzle (8 x 64).
// ---------------------------------------------------------------------------
__global__ __launch_bounds__(256) void gemm_out_kernel(const unsigned short* __restrict__ A,
                                                       const unsigned short* __restrict__ Bt,
                                                       const float* __restrict__ bias,
                                                       float* __restrict__ out) {
  __shared__ unsigned short As[64 * 64];    // 8 KB
  __shared__ unsigned short Bs[128 * 64];   // 16 KB
  int t = threadIdx.x, w = t >> 6, l = t & 63;
  int m16 = l & 15, q = l >> 4;
  int wm = w >> 1, wn = w & 1;          // wm 0..1 (32-token), wn 0..1 (64-feature)
  // XCD-bijective swizzle: 512 blocks = 8 XCDs x 64 -> 8 bm rows per XCD.
  int lid = blockIdx.y * 8 + blockIdx.x;
  int swz = (lid & 7) * 64 + (lid >> 3);
  int bn = swz & 7, bm = swz >> 3;
  const unsigned short* Abase = A + (size_t)bm * 64 * 1024;
  const unsigned short* Bbase = Bt + (size_t)bn * 128 * 1024;
  f32x4 zero4 = {0.f, 0.f, 0.f, 0.f};
  f32x4 acc[2][4];
#pragma unroll
  for (int i = 0; i < 2; ++i)
#pragma unroll
    for (int j = 0; j < 4; ++j) acc[i][j] = zero4;
  for (int kt = 0; kt < 16; ++kt) {
    stage_rows64_8w(As, Abase + kt * 64, 1024, w, l);   // w 0..3 covers rows 0..63
    stage_rows64(Bs, Bbase + kt * 64, 1024, w, l);      // 4-wave, 128 rows
    __syncthreads();
#pragma unroll
    for (int ks = 0; ks < 2; ++ks) {
      bs8 af[2], bf[4];
#pragma unroll
      for (int mt = 0; mt < 2; ++mt) {
        int row = wm * 32 + mt * 16 + m16;
        int c = ks * 4 + q;
        af[mt] = *(const bs8*)&As[row * 64 + ((c ^ (row & 7)) * 8)];
      }
#pragma unroll
      for (int nt = 0; nt < 4; ++nt) {
        int row = wn * 64 + nt * 16 + m16;
        int c = ks * 4 + q;
        bf[nt] = *(const bs8*)&Bs[row * 64 + ((c ^ (row & 7)) * 8)];
      }
#pragma unroll
      for (int mt = 0; mt < 2; ++mt)
#pragma unroll
        for (int nt = 0; nt < 4; ++nt)
          acc[mt][nt] = __builtin_amdgcn_mfma_f32_16x16x32_bf16(bf[nt], af[mt],
                                                                acc[mt][nt], 0, 0, 0);
    }
    __syncthreads();
  }
#pragma unroll
  for (int nt = 0; nt < 4; ++nt) {
    int ng0 = bn * 128 + wn * 64 + nt * 16 + q * 4;
    float4 bb = *(const float4*)&bias[ng0];
#pragma unroll
    for (int mt = 0; mt < 2; ++mt) {
      int mg = bm * 64 + wm * 32 + mt * 16 + m16;
      float4 ov;
      ov.x = acc[mt][nt][0] + bb.x;
      ov.y = acc[mt][nt][1] + bb.y;
      ov.z = acc[mt][nt][2] + bb.z;
      ov.w = acc[mt][nt][3] + bb.w;
      *(float4*)&out[(size_t)mg * 1024 + ng0] = ov;
    }
  }
}

// ---------------------------------------------------------------------------
// Flash attention on 32x32x16 MFMAs, S^T formulation, static-max softmax.
// grid = 512 blocks XCD-swizzled (8 x 64 -> 4 bh per XCD), 512 thr / 8 waves.
// Wave w: queries (w&3)*32..+31, keys (w>>2)*64..+63 of each 128-key tile.
// 16 iters, one barrier/iter, K/Vt double-buffered (64KB).
// QK: sAcc[tile] = mfma_32x32x16(K,Q) -> S^T[key][query]. exp2 in place;
// cvt_pk packs key pairs; permlane32_swap x2 per 16-key step -> exact
// 32x32x16 B-fragment. PV full rate. lsum = scalar adds. Epilogue restaged
// through LDS for coalesced store.  [= R16 body exactly]
// ---------------------------------------------------------------------------
__global__ __launch_bounds__(512, 4) void attn_kernel(const unsigned short* __restrict__ Q,
                                                      const unsigned short* __restrict__ K,
                                                      const unsigned short* __restrict__ Vt,
                                                      unsigned short* __restrict__ Aout) {
  __shared__ unsigned short Ks[2][128 * 64];    // 32 KB
  __shared__ unsigned short Vts[2][64 * 128];   // 32 KB
  int t = threadIdx.x, w = t >> 6, l = t & 63;
  int c32 = l & 31, lh = l >> 5;                // query column / lane half
  int wq = w & 3, kh = w >> 2;                  // query group / key half
  // XCD-bijective swizzle: 512 blocks = 8 XCDs x 64; each XCD owns 4 bh.
  int lid = blockIdx.y * 16 + blockIdx.x;
  int swz = (lid & 7) * 64 + (lid >> 3);
  int qt = swz & 15, bh = swz >> 4;
  const unsigned short* qbase = Q + (size_t)bh * 2048 * 64 + (size_t)qt * 128 * 64;
  const unsigned short* kbase = K + (size_t)bh * 2048 * 64;
  const unsigned short* vtbase = Vt + (size_t)bh * 64 * 2048;

  // Q fragments (B-operand): qf[ks] = Q[wq*32+c32][ks*16 + lh*8 ..+7]
  bs8 qf[4];
#pragma unroll
  for (int ks = 0; ks < 4; ++ks)
    qf[ks] = *(const bs8*)(qbase + (size_t)(wq * 32 + c32) * 64 + ks * 16 + lh * 8);

  stage_rows64_8w(&Ks[0][0], kbase, 64, w, l);
  stage_vt_8w(&Vts[0][0], vtbase, 0, w, l);
  __syncthreads();

  f32x16 sAcc[2];
  f32x16 o[2];
  float lsum = 0.f;
#pragma unroll
  for (int r = 0; r < 16; ++r) { o[0][r] = 0.f; o[1][r] = 0.f; }

  for (int kt = 0; kt < 16; ++kt) {
    int buf = kt & 1;
    if (kt < 15) {
      stage_rows64_8w(&Ks[buf ^ 1][0], kbase + (size_t)(kt + 1) * 128 * 64, 64, w, l);
      stage_vt_8w(&Vts[buf ^ 1][0], vtbase, (kt + 1) * 128, w, l);
    }
    const unsigned short* Kb = &Ks[buf][0];
    const unsigned short* Vb = &Vts[buf][0];

    // ---- S^T tiles over this wave's 64 keys (2 x 32-key tiles)
#pragma unroll
    for (int tile = 0; tile < 2; ++tile)
#pragma unroll
      for (int r = 0; r < 16; ++r) sAcc[tile][r] = -MBOUND;
#pragma unroll
    for (int ks = 0; ks < 4; ++ks) {
      int row0 = kh * 64 + c32;
      int row1 = row0 + 32;
      int cgr = ks * 2 + lh;
      bs8 kf0 = *(const bs8*)&Kb[row0 * 64 + ((cgr ^ (row0 & 7)) * 8)];
      bs8 kf1 = *(const bs8*)&Kb[row1 * 64 + ((cgr ^ (row1 & 7)) * 8)];
      __builtin_amdgcn_s_setprio(1);
      sAcc[0] = __builtin_amdgcn_mfma_f32_32x32x16_bf16(kf0, qf[ks], sAcc[0], 0, 0, 0);
      sAcc[1] = __builtin_amdgcn_mfma_f32_32x32x16_bf16(kf1, qf[ks], sAcc[1], 0, 0, 0);
      __builtin_amdgcn_s_setprio(0);
    }

    // ---- per tile: exp2 + cvt_pk pack + permlane redistribute + PV
#pragma unroll
    for (int tile = 0; tile < 2; ++tile) {
      float rs = 0.f;
      unsigned int wp[8];
#pragma unroll
      for (int ri = 0; ri < 8; ++ri) {
        float p0 = __builtin_amdgcn_exp2f(sAcc[tile][2 * ri]);
        float p1 = __builtin_amdgcn_exp2f(sAcc[tile][2 * ri + 1]);
        rs += p0 + p1;
        wp[ri] = cvtpk(p0, p1);
      }
      lsum += rs;
#pragma unroll
      for (int kp = 0; kp < 2; ++kp) {
        int ks2 = tile * 2 + kp;                // 16-key step within 64
        unsigned int W0 = wp[kp * 4 + 0], W2 = wp[kp * 4 + 2];
        unsigned int W1 = wp[kp * 4 + 1], W3 = wp[kp * 4 + 3];
        pls32(W0, W2);                          // -> B words 0 and 2
        pls32(W1, W3);                          // -> B words 1 and 3
        union { bs8 v; unsigned int u[4]; } pf;
        pf.u[0] = W0; pf.u[1] = W1; pf.u[2] = W2; pf.u[3] = W3;
        __builtin_amdgcn_s_setprio(1);
#pragma unroll
        for (int nh = 0; nh < 2; ++nh) {
          int vrow = nh * 32 + c32;
          int gk = kh * 8 + ks2 * 2 + lh;       // 8-key granule in 128-key row
          bs8 vf = *(const bs8*)&Vb[vrow * 128 + ((gk ^ (vrow & 15)) * 8)];
          o[nh] = __builtin_amdgcn_mfma_f32_32x32x16_bf16(vf, pf.v, o[nh], 0, 0, 0);
        }
        __builtin_amdgcn_s_setprio(0);
      }
    }
    __syncthreads();
  }

  // ---- cross-key-half combine. ored in Ks (32KB); lred in Vts[1] (1KB);
  // ot (bf16 O restage) in Vts[0] (16KB) -- disjoint regions, no race.
  float* ored = (float*)&Ks[0][0];
  float* lred = (float*)&Vts[1][0];
  unsigned short* ot = &Vts[0][0];
  int b = bh >> 4, hh = bh & 15;
  if (kh == 1) {
#pragma unroll
    for (int nh = 0; nh < 2; ++nh)
#pragma unroll
      for (int c = 0; c < 4; ++c) {
        f32x4 t4 = { o[nh][c * 4 + 0], o[nh][c * 4 + 1],
                     o[nh][c * 4 + 2], o[nh][c * 4 + 3] };
        *(f32x4*)&ored[((nh * 4 + c) * 256 + wq * 64 + l) * 4] = t4;
      }
    lred[wq * 64 + l] = lsum;
  }
  __syncthreads();
  if (kh == 0) {
#pragma unroll
    for (int nh = 0; nh < 2; ++nh)
#pragma unroll
      for (int c = 0; c < 4; ++c) {
        f32x4 part = *(const f32x4*)&ored[((nh * 4 + c) * 256 + wq * 64 + l) * 4];
#pragma unroll
        for (int r = 0; r < 4; ++r) o[nh][c * 4 + r] += part[r];
      }
    lsum += lred[wq * 64 + l];

    // lane halves hold the same query but disjoint key subsets -> xor-32 sum
    float l0 = lsum;
    l0 += __shfl_xor(l0, 32);
    float inv = 1.0f / l0;

    int token = wq * 32 + c32;
#pragma unroll
    for (int nh = 0; nh < 2; ++nh)
#pragma unroll
      for (int rg = 0; rg < 4; ++rg) {
        union { bs4 v; unsigned int u[2]; } pv;
        pv.u[0] = cvtpk(o[nh][rg * 4 + 0] * inv, o[nh][rg * 4 + 1] * inv);
        pv.u[1] = cvtpk(o[nh][rg * 4 + 2] * inv, o[nh][rg * 4 + 3] * inv);
        int g = nh * 4 + rg;                    // 16B hd-granule index
        *(bs4*)&ot[token * 64 + ((g ^ (token & 7)) * 8) + lh * 4] = pv.v;
      }
  }
  __syncthreads();
  // ---- coalesced store: 2 passes x 512 threads x 16B = full 128B per token
#pragma unroll
  for (int ps = 0; ps < 2; ++ps) {
    int idx = ps * 512 + t;
    int token = idx >> 3, g = idx & 7;
    bs8 val = *(const bs8*)&ot[token * 64 + ((g ^ (token & 7)) * 8)];
    *(bs8*)&Aout[((size_t)(b * 2048 + qt * 128 + token)) * 1024 + hh * 64 + g * 8] = val;
  }
}

// ---------------------------------------------------------------------------
extern "C" void kernel_launch(void* const* d_in, const int* in_sizes, int n_in,
                              void* d_out, int out_size, void* d_ws, size_t ws_size,
                              hipStream_t stream) {
  const float* x     = (const float*)d_in[0];   // [2,2048,1024]
  const float* w_qkv = (const float*)d_in[1];   // [1024,3072]
  const float* b_qkv = (const float*)d_in[2];   // [3072]
  const float* w_out = (const float*)d_in[3];   // [1024,1024]
  const float* b_out = (const float*)d_in[4];   // [1024]
  float* out = (float*)d_out;                   // [2,2048,1024] fp32

  char* ws = (char*)d_ws;                       // needs 48 MB
  unsigned short* xb    = (unsigned short*)(ws);                     // 8 MB
  unsigned short* wt1   = (unsigned short*)(ws + (8u << 20));        // 6 MB
  unsigned short* wt2   = (unsigned short*)(ws + (14u << 20));       // 2 MB
  unsigned short* qb    = (unsigned short*)(ws + (16u << 20));       // 8 MB
  unsigned short* kb    = (unsigned short*)(ws + (24u << 20));       // 8 MB
  unsigned short* vtb   = (unsigned short*)(ws + (32u << 20));       // 8 MB
  unsigned short* attnb = (unsigned short*)(ws + (40u << 20));       // 8 MB

  prep_kernel<<<3072, 256, 0, stream>>>(x, xb, w_qkv, wt1, w_out, wt2);
  gemm_qkv_kernel<<<dim3(24, 32), 256, 0, stream>>>(xb, wt1, b_qkv, qb, kb, vtb);
  attn_kernel<<<dim3(16, 32), 512, 0, stream>>>(qb, kb, vtb, attnb);
  gemm_out_kernel<<<dim3(8, 64), 256, 0, stream>>>(attnb, wt2, b_out, out);
}